// Round 13
// baseline (150.227 us; speedup 1.0000x reference)
//
#include <hip/hip_runtime.h>

#define DIM 32
#define NB  6
#define INV2PI 0.15915494309189535f

typedef __attribute__((ext_vector_type(8)))  _Float16 half8;
typedef __attribute__((ext_vector_type(16))) float floatx16;

union H8I4 { half8 h; int i[4]; };

// RNE f32x2 -> packed f16x2 (prologue only, cost irrelevant)
__device__ __forceinline__ int pkrne(float a, float b) {
    _Float16 h0 = (_Float16)a, h1 = (_Float16)b;
    unsigned short u0, u1;
    __builtin_memcpy(&u0, &h0, 2); __builtin_memcpy(&u1, &h1, 2);
    return (int)(u0 | ((unsigned)u1 << 16));
}
// RTZ f32x2 -> packed f16x2, single v_cvt_pkrtz_f16_f32 (hot path)
#if __has_builtin(__builtin_amdgcn_cvt_pkrtz)
__device__ __forceinline__ int pkrtz(float a, float b) {
    auto h = __builtin_amdgcn_cvt_pkrtz(a, b);
    int r; __builtin_memcpy(&r, &h, 4); return r;
}
#else
#define pkrtz pkrne
#endif

// B-frag slot (s,h,j) holds raw channel P; C/D reg (r,h) holds raw channel Q.
__device__ __forceinline__ int Pmap(int s, int h, int j) { return 16*s + 8*(j>>2) + 4*h + (j&3); }
__device__ __forceinline__ int Qmap(int p)               { int r = p & 15, h = p >> 4; return 8*(r>>2) + 4*h + (r&3); }

#define MFMA(a, b, c) __builtin_amdgcn_mfma_f32_32x32x16_f16((a), (b), (c), 0, 0, 0)

// acc in revolution domain (weights prescaled by 1/2pi): raw v_sin, then
// single-f16 activation pack via v_cvt_pkrtz (R2: measured 87us, absmax 9.8e-4).
__device__ __forceinline__ void sinsplit(const floatx16& acc, half8& b1, half8& b2) {
    H8I4 n1, n2;
    #pragma unroll
    for (int q = 0; q < 4; ++q) {
        n1.i[q] = pkrtz(__builtin_amdgcn_sinf(acc[2*q]),
                        __builtin_amdgcn_sinf(acc[2*q+1]));
        n2.i[q] = pkrtz(__builtin_amdgcn_sinf(acc[8+2*q]),
                        __builtin_amdgcn_sinf(acc[8+2*q+1]));
    }
    b1 = n1.h; b2 = n2.h;
}

// LDS: 224 floats (896 B) + (16384+1536+1536+256) shorts (39424 B) = 40320 B
// -> 2 blocks/CU uses 80,640 of 163,840.
#define LDS_BYTES 40320

// NOTE: __launch_bounds__ arg2 = min BLOCKS/CU on this toolchain.
// Geometry history (all measured):
//   R6  1-tile, 4 blk/CU: 62.7us | R8 2-tile, 2 blk/CU: 59.9us |
//   R9  2-tile, 4 blk/CU: 67us (ILP+TLP don't compose — CLOSED) |
//   R12 +prologue split: 59.0-59.2us <- base for this round.
// Spill tripwire: hbm_bytes (clean ~5 MB; spilled R1 was 2.3 GB).
// R1 lesson: sched_barrier(0) per layer is a LOAD-HOISTING FENCE. DO NOT REMOVE.
// R4 lesson (-7%): loads must be at REGION TOP (fence at layer start).
// R5/R6: Cf/Cg folded into inject-MFMA k-channels 6,7 (B carries 1.0).
// R7 lesson: inject-at-chain-head REGRESSED. Weight MFMAs first, inject LAST.
// R7+R10 (TWO clean failures): persistent zero C-bank is ALWAYS discarded by
// the compiler; zero-init v_movs are structural latency cover. NEVER retry.
// R11 BUG (NaN, fixed R12): fold guards must be 32 threads per 32-elem fold.
// R12: P3 split (Cf tid<192, Cg tid 192-383) + l=0 folds hoisted to P2. +1.5%.
// R13: 1-deep frag prefetch — pf0/pf1 hold the NEXT region's chain-head pair
// (ah0/ah1 or wz0/wz1), loaded one region ahead so chain-head MFMAs never
// wait on lgkmcnt (~55cyc stall/layer-block measured gap model). Late-use
// frags (ia/gi/wh) stay in-region (covered by >=2 MFMAs). +8 VGPR; per-region
// load count unchanged (<=5, R1 guard); fences unchanged.
__global__ __launch_bounds__(512, 2) void sep_mfma(
    const float* __restrict__ coords,
    const float* __restrict__ x_params,
    const float* __restrict__ t_params,
    const float* __restrict__ xW1, const float* __restrict__ xb1,
    const float* __restrict__ xW2, const float* __restrict__ xb2,
    const float* __restrict__ tW1, const float* __restrict__ tb1,
    const float* __restrict__ tW2, const float* __restrict__ tb2,
    const float* __restrict__ h0,  const float* __restrict__ gh0,
    const float* __restrict__ f_Wh, const float* __restrict__ f_bh,
    const float* __restrict__ f_Wz, const float* __restrict__ f_bz,
    const float* __restrict__ g_Wh, const float* __restrict__ g_bh,
    const float* __restrict__ g_Wz, const float* __restrict__ g_bz,
    const float* __restrict__ d_W,  const float* __restrict__ d_b,
    float* __restrict__ out)
{
    extern __shared__ char smem[];
    float* sdWp   = (float*)smem;            // [32] d_W (permuted via Qmap, NOT scaled)
    float* shx    = sdWp + 32;
    float* sht    = shx + 32;
    float* sex    = sht + 32;
    float* set_   = sex + 32;
    float* sFold  = set_ + 32;               // [64]: h0@f_Wh fold (0..31), gh0@g_Wh fold (32..63)
    // image: [f_Wh l=1..5 | g_Wh l=1..5 | g_Wz l=0..5] x [2 s-halves x 512], f16
    unsigned short* sImg  = (unsigned short*)(sFold + 64); // 16 slots * 1024 shorts
    // f-inject A-frags: per f-layer 32 rows x 8 f16
    // [z0h,z0h,z0l,z1h,z1h,z1l,CfH,CfL] (hi/lo split, prescaled by 1/2pi)
    unsigned short* sInj  = sImg + 16384;                  // 6 * 256 shorts
    // g-inject A-frags: [0,0,0,0,0,0,CgH,CgL]
    unsigned short* sGnj  = sInj + 1536;                   // 6 * 256 shorts
    unsigned short* sZero = sGnj + 1536;                   // 256 shorts of zeros (hg=1 A half)

    const int tid = threadIdx.x;
    const int b   = blockIdx.x >> 5;          // 32 blocks per batch
    const int ig  = blockIdx.x & 31;          // i-group: 8 i's per block

    // ================= PROLOGUE =================
    // P1: encoder stage 1 + weight A-frag image build (RNE f16, prescaled,
    // packed 2 channels per int store; l=0 of f_Wh/g_Wh folded -> omitted)
    if (tid < 32) {
        float a = xb1[tid];
        for (int k = 0; k < 16; ++k) a = fmaf(x_params[b * 16 + k], xW1[k * 32 + tid], a);
        shx[tid] = __sinf(a);
    } else if (tid < 64) {
        int d = tid - 32;
        float a = tb1[d];
        for (int k = 0; k < 8; ++k) a = fmaf(t_params[b * 8 + k], tW1[k * 32 + d], a);
        sht[d] = __sinf(a);
    }
    if (tid < 128) ((int*)sZero)[tid] = 0;
    {
        int* sImgI = (int*)sImg;
        for (int ii = tid; ii < 8192; ii += 512) {
            int region = ii >> 9;             // slot index 0..15 (block-uniform)
            int r = ii & 511;
            int s = r >> 8, t = r & 255;
            int lane = t >> 2, jj2 = t & 3;
            int m = lane & 31, hg = lane >> 5;
            int c0 = 16*s + 8*(jj2 >> 1) + 4*hg + 2*(jj2 & 1);  // Pmap(s,hg,2*jj2)
            float w0, w1;
            if (region < 5)       { int l = region + 1;  w0 = f_Wh[(l*32 + c0)*32 + m]; w1 = f_Wh[(l*32 + c0 + 1)*32 + m]; }
            else if (region < 10) { int l = region - 4;  w0 = g_Wh[(l*32 + c0)*32 + m]; w1 = g_Wh[(l*32 + c0 + 1)*32 + m]; }
            else                  { int l = region - 10; w0 = g_Wz[(l*64 + c0)*32 + m]; w1 = g_Wz[(l*64 + c0 + 1)*32 + m]; }
            sImgI[ii] = pkrne(w0 * INV2PI, w1 * INV2PI);
        }
    }
    __syncthreads();

    // P2: encoder stage 2 (4-way partial sums) + inject z0/z1 channels +
    // dWp + l=0 fold dots: tid [256,288) -> h0 fold, tid [288,320) -> gh0
    // fold. 32 threads per 32-element fold (R11 bug was 64-wide guards).
    if (tid < 32) {
        float a0 = xb2[tid], a1 = 0.f, a2 = 0.f, a3 = 0.f;
        #pragma unroll
        for (int c = 0; c < 32; c += 4) {
            a0 = fmaf(shx[c],     xW2[(c)     * 32 + tid], a0);
            a1 = fmaf(shx[c + 1], xW2[(c + 1) * 32 + tid], a1);
            a2 = fmaf(shx[c + 2], xW2[(c + 2) * 32 + tid], a2);
            a3 = fmaf(shx[c + 3], xW2[(c + 3) * 32 + tid], a3);
        }
        sex[tid] = (a0 + a1) + (a2 + a3);
    } else if (tid < 64) {
        int d = tid - 32;
        float a0 = tb2[d], a1 = 0.f, a2 = 0.f, a3 = 0.f;
        #pragma unroll
        for (int c = 0; c < 32; c += 4) {
            a0 = fmaf(sht[c],     tW2[(c)     * 32 + d], a0);
            a1 = fmaf(sht[c + 1], tW2[(c + 1) * 32 + d], a1);
            a2 = fmaf(sht[c + 2], tW2[(c + 2) * 32 + d], a2);
            a3 = fmaf(sht[c + 3], tW2[(c + 3) * 32 + d], a3);
        }
        set_[d] = (a0 + a1) + (a2 + a3);
    }
    if (tid >= 256 && tid < 288) {
        // h0 @ f_Wh[:,m] fold (exact 4-way order of the old P3 l==0 path)
        int m = tid - 256;
        float b0 = 0.f, b1 = 0.f, b2 = 0.f, b3 = 0.f;
        #pragma unroll
        for (int c = 0; c < 32; c += 4) {
            b0 = fmaf(h0[c],     f_Wh[(c)     * 32 + m], b0);
            b1 = fmaf(h0[c + 1], f_Wh[(c + 1) * 32 + m], b1);
            b2 = fmaf(h0[c + 2], f_Wh[(c + 2) * 32 + m], b2);
            b3 = fmaf(h0[c + 3], f_Wh[(c + 3) * 32 + m], b3);
        }
        sFold[m] = (b0 + b1) + (b2 + b3);
    } else if (tid >= 288 && tid < 320) {
        // gh0 @ g_Wh[:,m] fold
        int m = tid - 288;
        float c0_ = 0.f, c1_ = 0.f, c2_ = 0.f, c3_ = 0.f;
        #pragma unroll
        for (int c = 0; c < 32; c += 4) {
            c0_ = fmaf(gh0[c],     g_Wh[(c)     * 32 + m], c0_);
            c1_ = fmaf(gh0[c + 1], g_Wh[(c + 1) * 32 + m], c1_);
            c2_ = fmaf(gh0[c + 2], g_Wh[(c + 2) * 32 + m], c2_);
            c3_ = fmaf(gh0[c + 3], g_Wh[(c + 3) * 32 + m], c3_);
        }
        sFold[32 + m] = (c0_ + c1_) + (c2_ + c3_);
    }
    if (tid < 192) {
        // f-inject frag for layer l, output row m (RAW row: A-side mapping)
        int l = tid >> 5, m = tid & 31;
        float z0 = f_Wz[(l * 34 + 0) * 32 + m] * INV2PI;
        float z1 = f_Wz[(l * 34 + 1) * 32 + m] * INV2PI;
        _Float16 h0_ = (_Float16)z0; float z0h = (float)h0_, z0l = z0 - z0h;
        _Float16 h1_ = (_Float16)z1; float z1h = (float)h1_, z1l = z1 - z1h;
        int* p = (int*)sInj + 4 * tid;
        p[0] = pkrne(z0h, z0h);
        p[1] = pkrne(z0l, z1h);
        p[2] = pkrne(z1h, z1l);
        int* q = (int*)sGnj + 4 * tid;
        q[0] = 0; q[1] = 0; q[2] = 0;
    }
    if (tid < 32) sdWp[tid] = d_W[Qmap(tid)];
    __syncthreads();

    // P3 (split): Cf rows on tid<192, Cg rows on tid 192-383. l=0 fold from
    // sFold (added AFTER the Wz dot — same FP order as before).
    if (tid < 192) {
        int l = tid >> 5, m = tid & 31;
        float a0 = f_bh[l * 32 + m] + f_bz[l * 32 + m], a1 = 0.f, a2 = 0.f, a3 = 0.f;
        #pragma unroll
        for (int c = 0; c < 32; c += 4) {
            a0 = fmaf(set_[c],     f_Wz[(l * 34 + 2 + c) * 32 + m], a0);
            a1 = fmaf(set_[c + 1], f_Wz[(l * 34 + 3 + c) * 32 + m], a1);
            a2 = fmaf(set_[c + 2], f_Wz[(l * 34 + 4 + c) * 32 + m], a2);
            a3 = fmaf(set_[c + 3], f_Wz[(l * 34 + 5 + c) * 32 + m], a3);
        }
        float a = (a0 + a1) + (a2 + a3);
        if (l == 0) a += sFold[m];
        a *= INV2PI;
        _Float16 aH_ = (_Float16)a; float aH = (float)aH_, aL = a - aH;
        ((int*)sInj)[4 * tid + 3] = pkrne(aH, aL);
    } else if (tid < 384) {
        int r = tid - 192;
        int l = r >> 5, m = r & 31;
        float g0 = g_bh[l * 32 + m] + g_bz[l * 32 + m], g1 = 0.f, g2 = 0.f, g3 = 0.f;
        #pragma unroll
        for (int c = 0; c < 32; c += 4) {
            g0 = fmaf(sex[c],     g_Wz[(l * 64 + 32 + c)     * 32 + m], g0);
            g1 = fmaf(sex[c + 1], g_Wz[(l * 64 + 32 + c + 1) * 32 + m], g1);
            g2 = fmaf(sex[c + 2], g_Wz[(l * 64 + 32 + c + 2) * 32 + m], g2);
            g3 = fmaf(sex[c + 3], g_Wz[(l * 64 + 32 + c + 3) * 32 + m], g3);
        }
        float g = (g0 + g1) + (g2 + g3);
        if (l == 0) g += sFold[32 + m];
        g *= INV2PI;
        _Float16 gH_ = (_Float16)g; float gH = (float)gH_, gL = g - gH;
        ((int*)sGnj)[4 * r + 3] = pkrne(gH, gL);
    }
    __syncthreads();

    // ================= MAIN =================
    const int lane = tid & 63, wave = tid >> 6;
    const int i = ig * 8 + wave;
    const int e = lane & 31, hk = lane >> 5;
    const int pb = hk * 16;
    const float ti = coords[(b * 256 + i) * 2 + 1];
    const float db = d_b[0];

    // hi/lo split of ti (wave-uniform), hoisted out of the tile loop
    float th_, tl_;
    { _Float16 h = (_Float16)ti; th_ = (float)h; tl_ = ti - th_; }

    // inject A-frag bases: hg=0 lanes walk per layer; hg=1 lanes read the
    // shared zero block (their k-channels 8..15 are unused -> A rows exact 0,
    // which also makes hk=1 lanes' B content don't-care).
    const unsigned short* injbase = hk ? sZero : (sInj + e * 8);
    const unsigned short* gnjbase = hk ? sZero : (sGnj + e * 8);
    const int injstep = hk ? 0 : 256;   // shorts per layer

    // R13: prefetch pipeline seed — f l1's (ah0,ah1). Refreshed each region
    // with the NEXT region's chain-head pair; g l5 wraps back to f l1.
    half8 pf0, pf1;
    {
        const unsigned short* p0 = &sImg[lane * 8];
        pf0 = *(const half8*)(p0);
        pf1 = *(const half8*)(p0 + 512);
    }

    // R8: two tiles (jA, jB = jA+32) per iteration, interleaved independent
    // chains sharing all weight frags.
    #pragma unroll 1
    for (int t = 0; t < 4; ++t) {
        const int jA = (2 * t) * 32 + e;
        const int jB = jA + 32;
        const float xjA = coords[(b * 256 + jA) * 2];
        const float xjB = coords[(b * 256 + jB) * 2];

        // B-frags [xh,xl,xh,th,tl,th,1,1]: compensated hi/lo split; channels
        // 6,7 = 1.0 (exact f16) pick up the Cf/Cg fold from the A-side.
        half8 btA, btB;
        {
            float xh_, xl_;
            { _Float16 h = (_Float16)xjA; xh_ = (float)h; xl_ = xjA - xh_; }
            H8I4 u;
            u.i[0] = pkrtz(xh_, xl_);
            u.i[1] = pkrtz(xh_, th_);
            u.i[2] = pkrtz(tl_, th_);
            u.i[3] = 0x3C003C00;   // (1.0h, 1.0h)
            btA = u.h;
            { _Float16 h = (_Float16)xjB; xh_ = (float)h; xl_ = xjB - xh_; }
            u.i[0] = pkrtz(xh_, xl_);
            u.i[1] = pkrtz(xh_, th_);
            u.i[2] = pkrtz(tl_, th_);
            u.i[3] = 0x3C003C00;
            btB = u.h;
        }

        floatx16 accA, accB;
        half8 hA1, hA2, hB1, hB2;
        const unsigned short* ip = injbase;
        const unsigned short* gp = gnjbase;

        // ---- f layer 0: acc = inject(z0*x + z1*t + Cf0) from zero ----
        // ia0 is in-region (covered by bt setup + movs); pf holds f l1 pair.
        {
            half8 ia = *(const half8*)ip; ip += injstep;
            floatx16 zA, zB;
            #pragma unroll
            for (int r = 0; r < 16; ++r) { zA[r] = 0.0f; zB[r] = 0.0f; }
            accA = MFMA(ia, btA, zA);
            accB = MFMA(ia, btB, zB);
            sinsplit(accA, hA1, hA2);
            sinsplit(accB, hB1, hB2);
        }
        // ---- f layers 1..5: ah pair comes from PREFETCH (no lgkm wait);
        // ia in-region (used last, covered by 2 MFMAs); prefetch next pair.
        for (int l = 1; l < NB; ++l) {
            __builtin_amdgcn_sched_barrier(0);
            half8 ah0 = pf0, ah1 = pf1;
            half8 ia  = *(const half8*)ip; ip += injstep;
            {
                const unsigned short* nx = (l < NB - 1)
                    ? &sImg[(l * 2) * 512 + lane * 8]       // f ah pair, layer l+1
                    : &sImg[10240 + lane * 8];              // g wz pair, layer 0
                pf0 = *(const half8*)(nx);
                pf1 = *(const half8*)(nx + 512);
            }
            floatx16 zA, zB;
            #pragma unroll
            for (int r = 0; r < 16; ++r) { zA[r] = 0.0f; zB[r] = 0.0f; }
            zA = MFMA(ah0, hA1, zA);  zB = MFMA(ah0, hB1, zB);
            zA = MFMA(ah1, hA2, zA);  zB = MFMA(ah1, hB2, zB);
            accA = MFMA(ia, btA, zA); accB = MFMA(ia, btB, zB);
            sinsplit(accA, hA1, hA2);
            sinsplit(accB, hB1, hB2);
        }

        // ---- g layer 0: wz pair from PREFETCH; gi in-region (late-use);
        // prefetch g l1's wz pair. ----
        half8 gA1, gA2, gB1, gB2;
        {
            __builtin_amdgcn_sched_barrier(0);
            half8 wz0 = pf0, wz1 = pf1;
            half8 gi  = *(const half8*)gp; gp += injstep;
            {
                const unsigned short* nx = &sImg[10240 + 2 * 512 + lane * 8];
                pf0 = *(const half8*)(nx);
                pf1 = *(const half8*)(nx + 512);
            }
            floatx16 zA, zB;
            #pragma unroll
            for (int r = 0; r < 16; ++r) { zA[r] = 0.0f; zB[r] = 0.0f; }
            zA = MFMA(wz0, hA1, zA);  zB = MFMA(wz0, hB1, zB);
            zA = MFMA(wz1, hA2, zA);  zB = MFMA(wz1, hB2, zB);
            accA = MFMA(gi, btA, zA); accB = MFMA(gi, btB, zB);
            sinsplit(accA, gA1, gA2);
            sinsplit(accB, gB1, gB2);
        }
        // ---- g layers 1..5: wz pair from PREFETCH; wh pair + gi in-region
        // (wh used after 2 MFMAs, gi last); prefetch next wz pair, wrapping
        // to f l1's ah pair for the next j-iteration at l=5. ----
        for (int l = 1; l < NB; ++l) {
            __builtin_amdgcn_sched_barrier(0);
            half8 wz0 = pf0, wz1 = pf1;
            const unsigned short* bh = &sImg[5120 + ((l - 1) * 2) * 512 + lane * 8];
            half8 wh0 = *(const half8*)(bh);
            half8 wh1 = *(const half8*)(bh + 512);
            half8 gi  = *(const half8*)gp; gp += injstep;
            {
                const unsigned short* nx = (l < NB - 1)
                    ? &sImg[10240 + ((l + 1) * 2) * 512 + lane * 8]  // wz pair l+1
                    : &sImg[lane * 8];                               // f ah l1 (next iter)
                pf0 = *(const half8*)(nx);
                pf1 = *(const half8*)(nx + 512);
            }
            floatx16 zA, zB;
            #pragma unroll
            for (int r = 0; r < 16; ++r) { zA[r] = 0.0f; zB[r] = 0.0f; }
            zA = MFMA(wz0, hA1, zA);  zB = MFMA(wz0, hB1, zB);
            zA = MFMA(wz1, hA2, zA);  zB = MFMA(wz1, hB2, zB);
            zA = MFMA(wh0, gA1, zA);  zB = MFMA(wh0, gB1, zB);
            zA = MFMA(wh1, gA2, zA);  zB = MFMA(wh1, gB2, zB);
            accA = MFMA(gi, btA, zA); accB = MFMA(gi, btB, zB);
            if (l < NB - 1) {
                sinsplit(accA, gA1, gA2);
                sinsplit(accB, gB1, gB2);
            }
        }

        // ---- decode (both tiles) ----
        float uA = 0.0f, uB = 0.0f;
        #pragma unroll
        for (int r = 0; r < 16; ++r) {
            float w = sdWp[pb + r];
            uA = fmaf(__builtin_amdgcn_sinf(accA[r]), w, uA);
            uB = fmaf(__builtin_amdgcn_sinf(accB[r]), w, uB);
        }
        uA += __shfl_xor(uA, 32);
        uB += __shfl_xor(uB, 32);
        if (hk == 0) {
            out[(b * 256 + i) * 256 + jA] = uA + db;
            out[(b * 256 + i) * 256 + jB] = uB + db;
        }
    }
}

extern "C" void kernel_launch(void* const* d_in, const int* in_sizes, int n_in,
                              void* d_out, int out_size, void* d_ws, size_t ws_size,
                              hipStream_t stream) {
    const float* coords   = (const float*)d_in[0];
    const float* x_params = (const float*)d_in[1];
    const float* t_params = (const float*)d_in[2];
    const float* xW1 = (const float*)d_in[3];
    const float* xb1 = (const float*)d_in[4];
    const float* xW2 = (const float*)d_in[5];
    const float* xb2 = (const float*)d_in[6];
    const float* tW1 = (const float*)d_in[7];
    const float* tb1 = (const float*)d_in[8];
    const float* tW2 = (const float*)d_in[9];
    const float* tb2 = (const float*)d_in[10];
    const float* h0  = (const float*)d_in[11];
    const float* gh0 = (const float*)d_in[12];
    const float* f_Wh = (const float*)d_in[13];
    const float* f_bh = (const float*)d_in[14];
    const float* f_Wz = (const float*)d_in[15];
    const float* f_bz = (const float*)d_in[16];
    const float* g_Wh = (const float*)d_in[17];
    const float* g_bh = (const float*)d_in[18];
    const float* g_Wz = (const float*)d_in[19];
    const float* g_bz = (const float*)d_in[20];
    const float* d_W  = (const float*)d_in[21];
    const float* d_b  = (const float*)d_in[22];

    hipFuncSetAttribute((const void*)sep_mfma,
                        hipFuncAttributeMaxDynamicSharedMemorySize, LDS_BYTES);

    // 16 batches * 32 i-groups = 512 blocks of 512 threads
    // -> exactly 2 blocks/CU, fully co-resident; each block does 8 j-tiles
    // as 4 iterations of 2 interleaved tiles.
    sep_mfma<<<512, 512, LDS_BYTES, stream>>>(
        coords, x_params, t_params, xW1, xb1, xW2, xb2, tW1, tb1, tW2, tb2,
        h0, gh0, f_Wh, f_bh, f_Wz, f_bz, g_Wh, g_bh, g_Wz, g_bz, d_W, d_b,
        (float*)d_out);
}

// Round 14
// 145.840 us; speedup vs baseline: 1.0301x; 1.0301x over previous
//
#include <hip/hip_runtime.h>

#define DIM 32
#define NB  6
#define INV2PI 0.15915494309189535f

typedef __attribute__((ext_vector_type(8)))  _Float16 half8;
typedef __attribute__((ext_vector_type(16))) float floatx16;

union H8I4 { half8 h; int i[4]; };

// RNE f32x2 -> packed f16x2 (prologue only, cost irrelevant)
__device__ __forceinline__ int pkrne(float a, float b) {
    _Float16 h0 = (_Float16)a, h1 = (_Float16)b;
    unsigned short u0, u1;
    __builtin_memcpy(&u0, &h0, 2); __builtin_memcpy(&u1, &h1, 2);
    return (int)(u0 | ((unsigned)u1 << 16));
}
// RTZ f32x2 -> packed f16x2, single v_cvt_pkrtz_f16_f32 (hot path)
#if __has_builtin(__builtin_amdgcn_cvt_pkrtz)
__device__ __forceinline__ int pkrtz(float a, float b) {
    auto h = __builtin_amdgcn_cvt_pkrtz(a, b);
    int r; __builtin_memcpy(&r, &h, 4); return r;
}
#else
#define pkrtz pkrne
#endif

// B-frag slot (s,h,j) holds raw channel P; C/D reg (r,h) holds raw channel Q.
__device__ __forceinline__ int Pmap(int s, int h, int j) { return 16*s + 8*(j>>2) + 4*h + (j&3); }
__device__ __forceinline__ int Qmap(int p)               { int r = p & 15, h = p >> 4; return 8*(r>>2) + 4*h + (r&3); }

#define MFMA(a, b, c) __builtin_amdgcn_mfma_f32_32x32x16_f16((a), (b), (c), 0, 0, 0)

// acc in revolution domain (weights prescaled by 1/2pi): raw v_sin, then
// single-f16 activation pack via v_cvt_pkrtz (R2: measured 87us, absmax 9.8e-4).
__device__ __forceinline__ void sinsplit(const floatx16& acc, half8& b1, half8& b2) {
    H8I4 n1, n2;
    #pragma unroll
    for (int q = 0; q < 4; ++q) {
        n1.i[q] = pkrtz(__builtin_amdgcn_sinf(acc[2*q]),
                        __builtin_amdgcn_sinf(acc[2*q+1]));
        n2.i[q] = pkrtz(__builtin_amdgcn_sinf(acc[8+2*q]),
                        __builtin_amdgcn_sinf(acc[8+2*q+1]));
    }
    b1 = n1.h; b2 = n2.h;
}

// LDS: 224 floats (896 B) + (16384+1536+1536+256) shorts (39424 B) = 40320 B
// -> 2 blocks/CU uses 80,640 of 163,840.
#define LDS_BYTES 40320

// NOTE: __launch_bounds__ arg2 = min BLOCKS/CU on this toolchain.
// ===== SESSION LEDGER (all measured dispatch times) =====
// WINS: R2 f16 MFMA+cvt_pkrtz (119->87) | R3 coord-inject MFMA (87->72.6) |
//   R5/R6 Cf/Cg fold into inject ch6,7 (72.6->62.7) | R8 2-tile ILP at
//   2 blk/CU (62.7->59.9) | R12 prologue split (59.9->59.0).
// FAILURES (closed, do not retry):
//   R4 fence between MFMAs and loads (-7%): loads must be at REGION TOP.
//   R7/R10 persistent zero C-bank (2 clean fails): compiler always discards
//     it; zero-init v_movs are structural latency cover.
//   R9 2-tile at 4 blk/CU (-11%): ILP and TLP do NOT compose here.
//   R13 1-deep frag prefetch (-7%): prefetch live-ranges across regions
//     cost more than the lgkm wait they hide; in-region loads are already
//     covered by the other tile's chain.
// R1 lesson: sched_barrier(0) per layer is a LOAD-HOISTING FENCE. DO NOT REMOVE.
// R11 BUG (NaN, fixed R12): fold guards must be 32 threads per 32-elem fold.
// Spill tripwire: hbm_bytes (clean ~5 MB; spilled R1 was 2.3 GB).
// STATE: structural plateau — VALUBusy ~57%, MfmaUtil ~32%, trans-pipe
// (192 sins/tile) is the algorithmic floor; serial sin->pack->MFMA
// dependency absorbs the rest. This file = R12 verbatim (session best).
__global__ __launch_bounds__(512, 2) void sep_mfma(
    const float* __restrict__ coords,
    const float* __restrict__ x_params,
    const float* __restrict__ t_params,
    const float* __restrict__ xW1, const float* __restrict__ xb1,
    const float* __restrict__ xW2, const float* __restrict__ xb2,
    const float* __restrict__ tW1, const float* __restrict__ tb1,
    const float* __restrict__ tW2, const float* __restrict__ tb2,
    const float* __restrict__ h0,  const float* __restrict__ gh0,
    const float* __restrict__ f_Wh, const float* __restrict__ f_bh,
    const float* __restrict__ f_Wz, const float* __restrict__ f_bz,
    const float* __restrict__ g_Wh, const float* __restrict__ g_bh,
    const float* __restrict__ g_Wz, const float* __restrict__ g_bz,
    const float* __restrict__ d_W,  const float* __restrict__ d_b,
    float* __restrict__ out)
{
    extern __shared__ char smem[];
    float* sdWp   = (float*)smem;            // [32] d_W (permuted via Qmap, NOT scaled)
    float* shx    = sdWp + 32;
    float* sht    = shx + 32;
    float* sex    = sht + 32;
    float* set_   = sex + 32;
    float* sFold  = set_ + 32;               // [64]: h0@f_Wh fold (0..31), gh0@g_Wh fold (32..63)
    // image: [f_Wh l=1..5 | g_Wh l=1..5 | g_Wz l=0..5] x [2 s-halves x 512], f16
    unsigned short* sImg  = (unsigned short*)(sFold + 64); // 16 slots * 1024 shorts
    // f-inject A-frags: per f-layer 32 rows x 8 f16
    // [z0h,z0h,z0l,z1h,z1h,z1l,CfH,CfL] (hi/lo split, prescaled by 1/2pi)
    unsigned short* sInj  = sImg + 16384;                  // 6 * 256 shorts
    // g-inject A-frags: [0,0,0,0,0,0,CgH,CgL]
    unsigned short* sGnj  = sInj + 1536;                   // 6 * 256 shorts
    unsigned short* sZero = sGnj + 1536;                   // 256 shorts of zeros (hg=1 A half)

    const int tid = threadIdx.x;
    const int b   = blockIdx.x >> 5;          // 32 blocks per batch
    const int ig  = blockIdx.x & 31;          // i-group: 8 i's per block

    // ================= PROLOGUE =================
    // P1: encoder stage 1 + weight A-frag image build (RNE f16, prescaled,
    // packed 2 channels per int store; l=0 of f_Wh/g_Wh folded -> omitted)
    if (tid < 32) {
        float a = xb1[tid];
        for (int k = 0; k < 16; ++k) a = fmaf(x_params[b * 16 + k], xW1[k * 32 + tid], a);
        shx[tid] = __sinf(a);
    } else if (tid < 64) {
        int d = tid - 32;
        float a = tb1[d];
        for (int k = 0; k < 8; ++k) a = fmaf(t_params[b * 8 + k], tW1[k * 32 + d], a);
        sht[d] = __sinf(a);
    }
    if (tid < 128) ((int*)sZero)[tid] = 0;
    {
        int* sImgI = (int*)sImg;
        for (int ii = tid; ii < 8192; ii += 512) {
            int region = ii >> 9;             // slot index 0..15 (block-uniform)
            int r = ii & 511;
            int s = r >> 8, t = r & 255;
            int lane = t >> 2, jj2 = t & 3;
            int m = lane & 31, hg = lane >> 5;
            int c0 = 16*s + 8*(jj2 >> 1) + 4*hg + 2*(jj2 & 1);  // Pmap(s,hg,2*jj2)
            float w0, w1;
            if (region < 5)       { int l = region + 1;  w0 = f_Wh[(l*32 + c0)*32 + m]; w1 = f_Wh[(l*32 + c0 + 1)*32 + m]; }
            else if (region < 10) { int l = region - 4;  w0 = g_Wh[(l*32 + c0)*32 + m]; w1 = g_Wh[(l*32 + c0 + 1)*32 + m]; }
            else                  { int l = region - 10; w0 = g_Wz[(l*64 + c0)*32 + m]; w1 = g_Wz[(l*64 + c0 + 1)*32 + m]; }
            sImgI[ii] = pkrne(w0 * INV2PI, w1 * INV2PI);
        }
    }
    __syncthreads();

    // P2: encoder stage 2 (4-way partial sums) + inject z0/z1 channels +
    // dWp + l=0 fold dots: tid [256,288) -> h0 fold, tid [288,320) -> gh0
    // fold. 32 threads per 32-element fold (R11 bug was 64-wide guards).
    if (tid < 32) {
        float a0 = xb2[tid], a1 = 0.f, a2 = 0.f, a3 = 0.f;
        #pragma unroll
        for (int c = 0; c < 32; c += 4) {
            a0 = fmaf(shx[c],     xW2[(c)     * 32 + tid], a0);
            a1 = fmaf(shx[c + 1], xW2[(c + 1) * 32 + tid], a1);
            a2 = fmaf(shx[c + 2], xW2[(c + 2) * 32 + tid], a2);
            a3 = fmaf(shx[c + 3], xW2[(c + 3) * 32 + tid], a3);
        }
        sex[tid] = (a0 + a1) + (a2 + a3);
    } else if (tid < 64) {
        int d = tid - 32;
        float a0 = tb2[d], a1 = 0.f, a2 = 0.f, a3 = 0.f;
        #pragma unroll
        for (int c = 0; c < 32; c += 4) {
            a0 = fmaf(sht[c],     tW2[(c)     * 32 + d], a0);
            a1 = fmaf(sht[c + 1], tW2[(c + 1) * 32 + d], a1);
            a2 = fmaf(sht[c + 2], tW2[(c + 2) * 32 + d], a2);
            a3 = fmaf(sht[c + 3], tW2[(c + 3) * 32 + d], a3);
        }
        set_[d] = (a0 + a1) + (a2 + a3);
    }
    if (tid >= 256 && tid < 288) {
        // h0 @ f_Wh[:,m] fold (exact 4-way order of the old P3 l==0 path)
        int m = tid - 256;
        float b0 = 0.f, b1 = 0.f, b2 = 0.f, b3 = 0.f;
        #pragma unroll
        for (int c = 0; c < 32; c += 4) {
            b0 = fmaf(h0[c],     f_Wh[(c)     * 32 + m], b0);
            b1 = fmaf(h0[c + 1], f_Wh[(c + 1) * 32 + m], b1);
            b2 = fmaf(h0[c + 2], f_Wh[(c + 2) * 32 + m], b2);
            b3 = fmaf(h0[c + 3], f_Wh[(c + 3) * 32 + m], b3);
        }
        sFold[m] = (b0 + b1) + (b2 + b3);
    } else if (tid >= 288 && tid < 320) {
        // gh0 @ g_Wh[:,m] fold
        int m = tid - 288;
        float c0_ = 0.f, c1_ = 0.f, c2_ = 0.f, c3_ = 0.f;
        #pragma unroll
        for (int c = 0; c < 32; c += 4) {
            c0_ = fmaf(gh0[c],     g_Wh[(c)     * 32 + m], c0_);
            c1_ = fmaf(gh0[c + 1], g_Wh[(c + 1) * 32 + m], c1_);
            c2_ = fmaf(gh0[c + 2], g_Wh[(c + 2) * 32 + m], c2_);
            c3_ = fmaf(gh0[c + 3], g_Wh[(c + 3) * 32 + m], c3_);
        }
        sFold[32 + m] = (c0_ + c1_) + (c2_ + c3_);
    }
    if (tid < 192) {
        // f-inject frag for layer l, output row m (RAW row: A-side mapping)
        int l = tid >> 5, m = tid & 31;
        float z0 = f_Wz[(l * 34 + 0) * 32 + m] * INV2PI;
        float z1 = f_Wz[(l * 34 + 1) * 32 + m] * INV2PI;
        _Float16 h0_ = (_Float16)z0; float z0h = (float)h0_, z0l = z0 - z0h;
        _Float16 h1_ = (_Float16)z1; float z1h = (float)h1_, z1l = z1 - z1h;
        int* p = (int*)sInj + 4 * tid;
        p[0] = pkrne(z0h, z0h);
        p[1] = pkrne(z0l, z1h);
        p[2] = pkrne(z1h, z1l);
        int* q = (int*)sGnj + 4 * tid;
        q[0] = 0; q[1] = 0; q[2] = 0;
    }
    if (tid < 32) sdWp[tid] = d_W[Qmap(tid)];
    __syncthreads();

    // P3 (split): Cf rows on tid<192, Cg rows on tid 192-383. l=0 fold from
    // sFold (added AFTER the Wz dot — same FP order as before).
    if (tid < 192) {
        int l = tid >> 5, m = tid & 31;
        float a0 = f_bh[l * 32 + m] + f_bz[l * 32 + m], a1 = 0.f, a2 = 0.f, a3 = 0.f;
        #pragma unroll
        for (int c = 0; c < 32; c += 4) {
            a0 = fmaf(set_[c],     f_Wz[(l * 34 + 2 + c) * 32 + m], a0);
            a1 = fmaf(set_[c + 1], f_Wz[(l * 34 + 3 + c) * 32 + m], a1);
            a2 = fmaf(set_[c + 2], f_Wz[(l * 34 + 4 + c) * 32 + m], a2);
            a3 = fmaf(set_[c + 3], f_Wz[(l * 34 + 5 + c) * 32 + m], a3);
        }
        float a = (a0 + a1) + (a2 + a3);
        if (l == 0) a += sFold[m];
        a *= INV2PI;
        _Float16 aH_ = (_Float16)a; float aH = (float)aH_, aL = a - aH;
        ((int*)sInj)[4 * tid + 3] = pkrne(aH, aL);
    } else if (tid < 384) {
        int r = tid - 192;
        int l = r >> 5, m = r & 31;
        float g0 = g_bh[l * 32 + m] + g_bz[l * 32 + m], g1 = 0.f, g2 = 0.f, g3 = 0.f;
        #pragma unroll
        for (int c = 0; c < 32; c += 4) {
            g0 = fmaf(sex[c],     g_Wz[(l * 64 + 32 + c)     * 32 + m], g0);
            g1 = fmaf(sex[c + 1], g_Wz[(l * 64 + 32 + c + 1) * 32 + m], g1);
            g2 = fmaf(sex[c + 2], g_Wz[(l * 64 + 32 + c + 2) * 32 + m], g2);
            g3 = fmaf(sex[c + 3], g_Wz[(l * 64 + 32 + c + 3) * 32 + m], g3);
        }
        float g = (g0 + g1) + (g2 + g3);
        if (l == 0) g += sFold[32 + m];
        g *= INV2PI;
        _Float16 gH_ = (_Float16)g; float gH = (float)gH_, gL = g - gH;
        ((int*)sGnj)[4 * r + 3] = pkrne(gH, gL);
    }
    __syncthreads();

    // ================= MAIN (R8 verbatim) =================
    const int lane = tid & 63, wave = tid >> 6;
    const int i = ig * 8 + wave;
    const int e = lane & 31, hk = lane >> 5;
    const int pb = hk * 16;
    const float ti = coords[(b * 256 + i) * 2 + 1];
    const float db = d_b[0];

    // hi/lo split of ti (wave-uniform), hoisted out of the tile loop
    float th_, tl_;
    { _Float16 h = (_Float16)ti; th_ = (float)h; tl_ = ti - th_; }

    // inject A-frag bases: hg=0 lanes walk per layer; hg=1 lanes read the
    // shared zero block (their k-channels 8..15 are unused -> A rows exact 0,
    // which also makes hk=1 lanes' B content don't-care).
    const unsigned short* injbase = hk ? sZero : (sInj + e * 8);
    const unsigned short* gnjbase = hk ? sZero : (sGnj + e * 8);
    const int injstep = hk ? 0 : 256;   // shorts per layer

    // R8: two tiles (jA, jB = jA+32) per iteration, interleaved independent
    // chains sharing all weight frags.
    #pragma unroll 1
    for (int t = 0; t < 4; ++t) {
        const int jA = (2 * t) * 32 + e;
        const int jB = jA + 32;
        const float xjA = coords[(b * 256 + jA) * 2];
        const float xjB = coords[(b * 256 + jB) * 2];

        // B-frags [xh,xl,xh,th,tl,th,1,1]: compensated hi/lo split; channels
        // 6,7 = 1.0 (exact f16) pick up the Cf/Cg fold from the A-side.
        half8 btA, btB;
        {
            float xh_, xl_;
            { _Float16 h = (_Float16)xjA; xh_ = (float)h; xl_ = xjA - xh_; }
            H8I4 u;
            u.i[0] = pkrtz(xh_, xl_);
            u.i[1] = pkrtz(xh_, th_);
            u.i[2] = pkrtz(tl_, th_);
            u.i[3] = 0x3C003C00;   // (1.0h, 1.0h)
            btA = u.h;
            { _Float16 h = (_Float16)xjB; xh_ = (float)h; xl_ = xjB - xh_; }
            u.i[0] = pkrtz(xh_, xl_);
            u.i[1] = pkrtz(xh_, th_);
            u.i[2] = pkrtz(tl_, th_);
            u.i[3] = 0x3C003C00;
            btB = u.h;
        }

        floatx16 accA, accB;
        half8 hA1, hA2, hB1, hB2;
        const unsigned short* ip = injbase;
        const unsigned short* gp = gnjbase;

        // ---- f layer 0: acc = inject(z0*x + z1*t + Cf0) from zero ----
        {
            half8 ia = *(const half8*)ip; ip += injstep;
            floatx16 zA, zB;
            #pragma unroll
            for (int r = 0; r < 16; ++r) { zA[r] = 0.0f; zB[r] = 0.0f; }
            accA = MFMA(ia, btA, zA);
            accB = MFMA(ia, btB, zB);
            sinsplit(accA, hA1, hA2);
            sinsplit(accB, hB1, hB2);
        }
        // ---- f layers 1..5: R6 order (Wh pair first, inject LAST), A/B
        // chains interleaved; frags shared. Fence at layer start. ----
        for (int l = 1; l < NB; ++l) {
            __builtin_amdgcn_sched_barrier(0);
            const unsigned short* base = &sImg[((l - 1) * 2) * 512 + lane * 8];
            half8 ah0 = *(const half8*)(base);
            half8 ah1 = *(const half8*)(base + 512);
            half8 ia  = *(const half8*)ip; ip += injstep;
            floatx16 zA, zB;
            #pragma unroll
            for (int r = 0; r < 16; ++r) { zA[r] = 0.0f; zB[r] = 0.0f; }
            zA = MFMA(ah0, hA1, zA);  zB = MFMA(ah0, hB1, zB);
            zA = MFMA(ah1, hA2, zA);  zB = MFMA(ah1, hB2, zB);
            accA = MFMA(ia, btA, zA); accB = MFMA(ia, btB, zB);
            sinsplit(accA, hA1, hA2);
            sinsplit(accB, hB1, hB2);
        }

        // ---- g layer 0: Wz pair (hX, ready) then g-inject(+Cg0) last ----
        half8 gA1, gA2, gB1, gB2;
        {
            __builtin_amdgcn_sched_barrier(0);
            const unsigned short* bz = &sImg[10240 + lane * 8];
            half8 wz0 = *(const half8*)(bz);
            half8 wz1 = *(const half8*)(bz + 512);
            half8 gi  = *(const half8*)gp; gp += injstep;
            floatx16 zA, zB;
            #pragma unroll
            for (int r = 0; r < 16; ++r) { zA[r] = 0.0f; zB[r] = 0.0f; }
            zA = MFMA(wz0, hA1, zA);  zB = MFMA(wz0, hB1, zB);
            zA = MFMA(wz1, hA2, zA);  zB = MFMA(wz1, hB2, zB);
            accA = MFMA(gi, btA, zA); accB = MFMA(gi, btB, zB);
            sinsplit(accA, gA1, gA2);
            sinsplit(accB, gB1, gB2);
        }
        // ---- g layers 1..5: Wz (hX) -> Wh (fresh gX) -> g-inject last ----
        for (int l = 1; l < NB; ++l) {
            __builtin_amdgcn_sched_barrier(0);
            const unsigned short* bz = &sImg[10240 + (l * 2) * 512 + lane * 8];
            const unsigned short* bh = &sImg[5120 + ((l - 1) * 2) * 512 + lane * 8];
            half8 wz0 = *(const half8*)(bz);
            half8 wz1 = *(const half8*)(bz + 512);
            half8 wh0 = *(const half8*)(bh);
            half8 wh1 = *(const half8*)(bh + 512);
            half8 gi  = *(const half8*)gp; gp += injstep;
            floatx16 zA, zB;
            #pragma unroll
            for (int r = 0; r < 16; ++r) { zA[r] = 0.0f; zB[r] = 0.0f; }
            zA = MFMA(wz0, hA1, zA);  zB = MFMA(wz0, hB1, zB);
            zA = MFMA(wz1, hA2, zA);  zB = MFMA(wz1, hB2, zB);
            zA = MFMA(wh0, gA1, zA);  zB = MFMA(wh0, gB1, zB);
            zA = MFMA(wh1, gA2, zA);  zB = MFMA(wh1, gB2, zB);
            accA = MFMA(gi, btA, zA); accB = MFMA(gi, btB, zB);
            if (l < NB - 1) {
                sinsplit(accA, gA1, gA2);
                sinsplit(accB, gB1, gB2);
            }
        }

        // ---- decode (both tiles) ----
        float uA = 0.0f, uB = 0.0f;
        #pragma unroll
        for (int r = 0; r < 16; ++r) {
            float w = sdWp[pb + r];
            uA = fmaf(__builtin_amdgcn_sinf(accA[r]), w, uA);
            uB = fmaf(__builtin_amdgcn_sinf(accB[r]), w, uB);
        }
        uA += __shfl_xor(uA, 32);
        uB += __shfl_xor(uB, 32);
        if (hk == 0) {
            out[(b * 256 + i) * 256 + jA] = uA + db;
            out[(b * 256 + i) * 256 + jB] = uB + db;
        }
    }
}

extern "C" void kernel_launch(void* const* d_in, const int* in_sizes, int n_in,
                              void* d_out, int out_size, void* d_ws, size_t ws_size,
                              hipStream_t stream) {
    const float* coords   = (const float*)d_in[0];
    const float* x_params = (const float*)d_in[1];
    const float* t_params = (const float*)d_in[2];
    const float* xW1 = (const float*)d_in[3];
    const float* xb1 = (const float*)d_in[4];
    const float* xW2 = (const float*)d_in[5];
    const float* xb2 = (const float*)d_in[6];
    const float* tW1 = (const float*)d_in[7];
    const float* tb1 = (const float*)d_in[8];
    const float* tW2 = (const float*)d_in[9];
    const float* tb2 = (const float*)d_in[10];
    const float* h0  = (const float*)d_in[11];
    const float* gh0 = (const float*)d_in[12];
    const float* f_Wh = (const float*)d_in[13];
    const float* f_bh = (const float*)d_in[14];
    const float* f_Wz = (const float*)d_in[15];
    const float* f_bz = (const float*)d_in[16];
    const float* g_Wh = (const float*)d_in[17];
    const float* g_bh = (const float*)d_in[18];
    const float* g_Wz = (const float*)d_in[19];
    const float* g_bz = (const float*)d_in[20];
    const float* d_W  = (const float*)d_in[21];
    const float* d_b  = (const float*)d_in[22];

    hipFuncSetAttribute((const void*)sep_mfma,
                        hipFuncAttributeMaxDynamicSharedMemorySize, LDS_BYTES);

    // 16 batches * 32 i-groups = 512 blocks of 512 threads
    // -> exactly 2 blocks/CU, fully co-resident; each block does 8 j-tiles
    // as 4 iterations of 2 interleaved tiles.
    sep_mfma<<<512, 512, LDS_BYTES, stream>>>(
        coords, x_params, t_params, xW1, xb1, xW2, xb2, tW1, tb1, tW2, tb2,
        h0, gh0, f_Wh, f_bh, f_Wz, f_bz, g_Wh, g_bh, g_Wz, g_bz, d_W, d_b,
        (float*)d_out);
}